// Round 6
// baseline (255.034 us; speedup 1.0000x reference)
//
#include <hip/hip_runtime.h>
#include <math.h>

// ---------------------------------------------------------------------------
// MambaAnglePredictor — Round 6:
//   phase2 serial carry -> parallel lower-triangular matmul (k_phase2p)
//   phase3 B/C transpose staging XOR-swizzled (conflict-free), stride 64
// ---------------------------------------------------------------------------

#define BDIM 4
#define LDIM 4096
#define BL (BDIM*LDIM)      // 16384 tokens
#define QC 64               // chunk length
#define NC (LDIM/QC)        // 64 chunks
#define BH (BDIM*NH)        // 32
#define NH 8

// workspace offsets (floats)
#define OFF_W    0u          // Weff_in 4x904 @0, beff @4096, Weff2 @8192 (12288)
#define OFF_Z    3145728u    // yn (normalized y) fp32 16384*384
#define OFF_T    9437184u    // T 2048*3072
#define OFF_XS   17825792u   // 32*4096*48
#define OFF_BM   24117248u   // 16384*64
#define OFF_CM   25165824u   // 16384*64
#define OFF_DT   26214400u   // 32*4096
#define OFF_LAC  26345472u   // 2048*64
#define OFF_SP   26476544u   // 2048*64*3072... (2048*3072)
#define OFF_Y    32768000u   // 16384*384 fp32
#define OFF_MACC 39059456u   // 4*32

__device__ __forceinline__ float sigmoidf_(float x){ return 1.0f/(1.0f+__expf(-x)); }

// ----- prep1: Weff_in[r][n] = sum_d Wfc[r][d] W_in[d][n]; beff[n] = bfc@W_in -----
__global__ void k_prep1(const float* __restrict__ Wfc, const float* __restrict__ bfc,
                        const float* __restrict__ W_in,
                        float* __restrict__ Weff, float* __restrict__ beff){
  int n = blockIdx.x*256 + threadIdx.x;
  if (n >= 904) return;
  float a0=0.f,a1=0.f,a2=0.f,a3=0.f,ab=0.f;
  for (int d=0; d<192; d++){
    float w = W_in[(size_t)d*904 + n];
    a0 = fmaf(Wfc[d], w, a0);
    a1 = fmaf(Wfc[192+d], w, a1);
    a2 = fmaf(Wfc[384+d], w, a2);
    a3 = fmaf(Wfc[576+d], w, a3);
    ab = fmaf(bfc[d], w, ab);
  }
  Weff[n] = a0; Weff[904+n] = a1; Weff[1808+n] = a2; Weff[2712+n] = a3;
  beff[n] = ab;
}

// ----- prep2: Weff2[i][j] = sum_d W_out[i][d] W1[d][j] (384x32) -----
__global__ void k_prep2(const float* __restrict__ W_out, const float* __restrict__ W1,
                        float* __restrict__ Weff2){
  int g = blockIdx.x*256 + threadIdx.x;   // 12288
  int i = g>>5, j = g&31;
  float a = 0.f;
  for (int d=0; d<192; d++) a = fmaf(W_out[(size_t)i*192+d], W1[d*32+j], a);
  Weff2[g] = a;
}

// ----- ipc: fused in_proj(xBC cols)+conv+silu+dt. One block per token. -----
__global__ __launch_bounds__(256) void k_ipc(
    const float* __restrict__ x, const float* __restrict__ Weff,
    const float* __restrict__ beff, const float* __restrict__ conv_w,
    const float* __restrict__ conv_b, const float* __restrict__ dt_bias,
    float* __restrict__ xs, float* __restrict__ Bm, float* __restrict__ Cm,
    float* __restrict__ dtb){
  __shared__ float sx[4][4];            // [k][r] for tokens l-3+k
  int bl = blockIdx.x, tid = threadIdx.x;
  int l = bl & 4095, b = bl >> 12;
  if (tid < 16){
    int k = tid>>2, r = tid&3;
    int ll = l-3+k;
    sx[k][r] = (ll>=0) ? x[(size_t)(b*4096+ll)*4 + r] : 0.f;
  }
  __syncthreads();
  // dt: cols 896..903
  if (tid < 8){
    float raw = beff[896+tid];
    #pragma unroll
    for (int r=0;r<4;r++) raw = fmaf(sx[3][r], Weff[r*904+896+tid], raw);
    float xx = raw + dt_bias[tid];
    float dtv = (xx > 20.f) ? xx : log1pf(__expf(xx));
    dtb[(size_t)(b*8+tid)*4096 + l] = dtv;
  }
  #pragma unroll
  for (int half=0; half<2; half++){
    int c = tid + half*256;             // xBC col 0..511 -> Weff col 384+c
    float w0 = Weff[384+c];
    float w1 = Weff[904+384+c];
    float w2 = Weff[1808+384+c];
    float w3 = Weff[2712+384+c];
    float bb = beff[384+c];
    float acc = conv_b[c];
    #pragma unroll
    for (int k=0;k<4;k++){
      int ll = l-3+k;
      float xv = bb;
      xv = fmaf(sx[k][0], w0, xv);
      xv = fmaf(sx[k][1], w1, xv);
      xv = fmaf(sx[k][2], w2, xv);
      xv = fmaf(sx[k][3], w3, xv);
      if (ll < 0) xv = 0.f;             // zero-pad is on xBC, pre-conv
      acc = fmaf(conv_w[k*512+c], xv, acc);
    }
    float v = acc * sigmoidf_(acc);
    if (c < 384){
      int hh = c / 48, p = c - hh*48;
      xs[(size_t)((b*8+hh)*4096 + l)*48 + p] = v;
    } else if (c < 448){
      Bm[(size_t)bl*64 + (c-384)] = v;
    } else {
      Cm[(size_t)bl*64 + (c-448)] = v;
    }
  }
}

// ----- phase1: per-chunk cumlog(dA), chunk state T_k = sum w_s B_s x_s^T -----
__global__ __launch_bounds__(256) void k_phase1(
    const float* __restrict__ dtbuf, const float* __restrict__ Bm,
    const float* __restrict__ xs, const float* __restrict__ A_log,
    float* __restrict__ T, float* __restrict__ lac){
  __shared__ float sdt[64], sla[64], sw[64];
  __shared__ __align__(16) float sBW[64][64];
  __shared__ __align__(16) float sX[64][48];
  int tid = threadIdx.x, blk = blockIdx.x;
  int bh = blk >> 6, k = blk & 63;
  int b = bh >> 3, hh = bh & 7;
  int t0 = k*64;
  if (tid < 64) sdt[tid] = dtbuf[(size_t)bh*4096 + t0 + tid];
  __syncthreads();
  if (tid == 0){
    float eA = __expf(A_log[hh]);
    float cum = 0.f;
    for (int i=0;i<64;i++){ cum -= sdt[i]*eA; sla[i] = cum; }
  }
  __syncthreads();
  if (tid < 64){
    sw[tid] = __expf(sla[63]-sla[tid])*sdt[tid];
    lac[(size_t)blk*64 + tid] = sla[tid];
  }
  __syncthreads();
  {
    int s = tid>>2, n0 = (tid&3)*16;
    float wsc = sw[s];
    const float* src = Bm + (size_t)(b*4096 + t0 + s)*64 + n0;
    #pragma unroll
    for (int q=0;q<4;q++){
      float4 v = *(const float4*)(src + q*4);
      v.x*=wsc; v.y*=wsc; v.z*=wsc; v.w*=wsc;
      *(float4*)&sBW[s][n0+q*4] = v;
    }
    int p0 = (tid&3)*12;
    const float* xsrc = xs + (size_t)(bh*4096 + t0 + s)*48 + p0;
    #pragma unroll
    for (int q=0;q<3;q++) *(float4*)&sX[s][p0+q*4] = *(const float4*)(xsrc + q*4);
  }
  __syncthreads();
  if (tid < 192){
    int n0 = (tid/12)*4, p0 = (tid%12)*4;
    float acc[4][4];
    #pragma unroll
    for (int i=0;i<4;i++)
      #pragma unroll
      for (int j=0;j<4;j++) acc[i][j]=0.f;
    for (int s=0;s<64;s++){
      float bw[4], xv[4];
      *(float4*)bw = *(float4*)&sBW[s][n0];
      *(float4*)xv = *(float4*)&sX[s][p0];
      #pragma unroll
      for (int i=0;i<4;i++)
        #pragma unroll
        for (int j=0;j<4;j++) acc[i][j] = fmaf(bw[i], xv[j], acc[i][j]);
    }
    float* dst = T + (size_t)blk*3072;
    #pragma unroll
    for (int i=0;i<4;i++){
      float4 o; o.x=acc[i][0]; o.y=acc[i][1]; o.z=acc[i][2]; o.w=acc[i][3];
      *(float4*)(dst + (n0+i)*48 + p0) = o;
    }
  }
}

// ----- phase2p: Sp[k] = sum_{j<k} W[k][j] T[j], W via serial product (exact) -----
// grid (32 bh, 48 e-slices of 64), 256 threads, 4x4 tiles.
__global__ __launch_bounds__(256) void k_phase2p(
    const float* __restrict__ T, const float* __restrict__ lac, float* __restrict__ Sp){
  __shared__ __align__(16) float sT[64*64];    // [j][e]
  __shared__ __align__(16) float sW[64][68];   // [j][k]
  __shared__ float sc[64];
  int tid = threadIdx.x;
  int bh = blockIdx.x, es = blockIdx.y;
  #pragma unroll
  for (int r=0;r<4;r++){
    int idx = tid + r*256;            // 1024 float4 = 64 rows x 16
    int row = idx>>4, c4 = (idx&15)*4;
    *(float4*)&sT[row*64 + c4] = *(const float4*)(T + (size_t)(bh*64+row)*3072 + es*64 + c4);
  }
  if (tid < 64) sc[tid] = __expf(lac[(size_t)(bh*64+tid)*64 + 63]);
  __syncthreads();
  if (tid < 64){
    int k = tid;
    float w = 1.f;
    for (int j=63; j>=0; --j){
      bool a = (j < k);
      sW[j][k] = a ? w : 0.f;
      if (a) w *= sc[j];
    }
  }
  __syncthreads();
  int k0 = (tid>>4)*4, e0 = (tid&15)*4;
  float acc[4][4];
  #pragma unroll
  for (int i=0;i<4;i++)
    #pragma unroll
    for (int j=0;j<4;j++) acc[i][j]=0.f;
  int jmax = k0+2; if (jmax > 62) jmax = 62;
  for (int j=0; j<=jmax; ++j){
    float wv[4], tv[4];
    *(float4*)wv = *(float4*)&sW[j][k0];
    *(float4*)tv = *(float4*)&sT[j*64 + e0];
    #pragma unroll
    for (int i=0;i<4;i++)
      #pragma unroll
      for (int e=0;e<4;e++) acc[i][e] = fmaf(wv[i], tv[e], acc[i][e]);
  }
  #pragma unroll
  for (int i=0;i<4;i++){
    float4 o; o.x=acc[i][0]; o.y=acc[i][1]; o.z=acc[i][2]; o.w=acc[i][3];
    *(float4*)(Sp + (size_t)(bh*64+k0+i)*3072 + es*64 + e0) = o;
  }
}

// ----- phase3: Y = (L o C B^T) X + diag(exp(la)) C S_prev + D*x -----
// B^T/C^T staged in stride-64 XOR-swizzled LDS: col = t ^ (n & 60).
__global__ __launch_bounds__(256, 3) void k_phase3(
    const float* __restrict__ dtbuf, const float* __restrict__ lac,
    const float* __restrict__ Bm, const float* __restrict__ Cm,
    const float* __restrict__ xs, const float* __restrict__ Sp,
    const float* __restrict__ Dparam, float* __restrict__ y){
  __shared__ __align__(16) float sBs[64*64];   // B^T swz [n][s] -> X [s][p] plain
  __shared__ __align__(16) float sCs[64*64];   // C^T swz [n][i]
  __shared__ __align__(16) float sSG[64][68];  // Sp [n][p] -> GM^T [s][i]
  __shared__ float sdt[64], sla[64];
  int tid = threadIdx.x, blk = blockIdx.x;
  int bh = blk>>6, k = blk&63, b = bh>>3, hh = bh&7, t0 = k*64;

  int rs = tid>>2, c0 = (tid&3)*12;
  float4 xpre0, xpre1, xpre2;
  {
    const float* xsrc = xs + (size_t)(bh*4096+t0+rs)*48 + c0;
    xpre0 = *(const float4*)(xsrc);
    xpre1 = *(const float4*)(xsrc+4);
    xpre2 = *(const float4*)(xsrc+8);
  }
  if (tid < 64){
    sdt[tid] = dtbuf[(size_t)bh*4096 + t0 + tid];
    sla[tid] = lac[(size_t)blk*64 + tid];
  }
  {
    const float* ssrc = Sp + (size_t)blk*3072 + rs*48 + c0;
    *(float4*)&sSG[rs][c0]   = *(const float4*)(ssrc);
    *(float4*)&sSG[rs][c0+4] = *(const float4*)(ssrc+4);
    *(float4*)&sSG[rs][c0+8] = *(const float4*)(ssrc+8);
  }
  {
    int s = tid>>2, n0 = (tid&3)*16;
    const float* bsrc = Bm + (size_t)(b*4096+t0+s)*64 + n0;
    const float* csrc = Cm + (size_t)(b*4096+t0+s)*64 + n0;
    #pragma unroll
    for (int q=0;q<4;q++){
      float4 bv = *(const float4*)(bsrc + q*4);
      float4 cv = *(const float4*)(csrc + q*4);
      #pragma unroll
      for (int c=0;c<4;c++){
        int n = n0 + q*4 + c;
        int col = s ^ (n & 60);
        float bvc = (c==0)?bv.x:(c==1)?bv.y:(c==2)?bv.z:bv.w;
        float cvc = (c==0)?cv.x:(c==1)?cv.y:(c==2)?cv.z:cv.w;
        sBs[n*64 + col] = bvc;
        sCs[n*64 + col] = cvc;
      }
    }
  }
  __syncthreads();

  int i0p = (tid/12)*4, p0 = (tid%12)*4;
  float acc[4][4];
  #pragma unroll
  for (int i=0;i<4;i++)
    #pragma unroll
    for (int j=0;j<4;j++) acc[i][j]=0.f;
  if (tid < 192){
    #pragma unroll 4
    for (int n=0;n<64;n++){
      float cv[4], sp[4];
      *(float4*)cv = *(float4*)&sCs[n*64 + (i0p ^ (n & 60))];
      *(float4*)sp = *(float4*)&sSG[n][p0];
      #pragma unroll
      for (int ii=0;ii<4;ii++)
        #pragma unroll
        for (int j=0;j<4;j++) acc[ii][j] = fmaf(cv[ii], sp[j], acc[ii][j]);
    }
  }
  int ig = (tid>>4)*4, sg = (tid&15)*4;
  float gm[4][4];
  #pragma unroll
  for (int i=0;i<4;i++)
    #pragma unroll
    for (int j=0;j<4;j++) gm[i][j]=0.f;
  if (sg <= ig+3){
    #pragma unroll 4
    for (int n=0;n<64;n++){
      float cv[4], bv[4];
      *(float4*)cv = *(float4*)&sCs[n*64 + (ig ^ (n & 60))];
      *(float4*)bv = *(float4*)&sBs[n*64 + (sg ^ (n & 60))];
      #pragma unroll
      for (int ii=0;ii<4;ii++)
        #pragma unroll
        for (int ss=0;ss<4;ss++) gm[ii][ss] = fmaf(cv[ii], bv[ss], gm[ii][ss]);
    }
    #pragma unroll
    for (int ii=0;ii<4;ii++)
      #pragma unroll
      for (int ss=0;ss<4;ss++){
        int i = ig+ii, s = sg+ss;
        gm[ii][ss] = (s<=i) ? gm[ii][ss]*__expf(sla[i]-sla[s])*sdt[s] : 0.f;
      }
  }
  __syncthreads();

  #pragma unroll
  for (int ss=0;ss<4;ss++){
    float4 o; o.x=gm[0][ss]; o.y=gm[1][ss]; o.z=gm[2][ss]; o.w=gm[3][ss];
    *(float4*)&sSG[sg+ss][ig] = o;
  }
  *(float4*)&sBs[rs*64 + c0]     = xpre0;
  *(float4*)&sBs[rs*64 + c0+4]   = xpre1;
  *(float4*)&sBs[rs*64 + c0+8]   = xpre2;
  if (tid < 192){
    #pragma unroll
    for (int ii=0;ii<4;ii++){
      float ci = __expf(sla[i0p+ii]);
      #pragma unroll
      for (int j=0;j<4;j++) acc[ii][j] *= ci;
    }
  }
  __syncthreads();

  if (tid < 192){
    for (int s0=0; s0<=i0p; s0+=4){
      #pragma unroll
      for (int q=0;q<4;q++){
        float gv[4], xv[4];
        *(float4*)gv = *(float4*)&sSG[s0+q][i0p];
        *(float4*)xv = *(float4*)&sBs[(s0+q)*64 + p0];
        #pragma unroll
        for (int ii=0;ii<4;ii++)
          #pragma unroll
          for (int j=0;j<4;j++) acc[ii][j] = fmaf(gv[ii], xv[j], acc[ii][j]);
      }
    }
    float Dh = Dparam[hh];
    #pragma unroll
    for (int ii=0;ii<4;ii++){
      int i = i0p+ii;
      float4 xd = *(float4*)&sBs[i*64 + p0];
      float4 o;
      o.x = acc[ii][0] + Dh*xd.x;
      o.y = acc[ii][1] + Dh*xd.y;
      o.z = acc[ii][2] + Dh*xd.z;
      o.w = acc[ii][3] + Dh*xd.w;
      *(float4*)(y + (size_t)(b*4096+t0+i)*384 + hh*48 + p0) = o;
    }
  }
}

// ----- gate: z recomputed from x (K=4); g=y*silu(z); RMSNorm; write yn -----
__global__ __launch_bounds__(384) void k_gate(
    const float* __restrict__ x, const float* __restrict__ Weff,
    const float* __restrict__ beff, const float* __restrict__ norm_w,
    const float* __restrict__ y, float* __restrict__ yn){
  __shared__ float sred[6];
  __shared__ float srms;
  __shared__ float sx[4];
  int bl = blockIdx.x, tid = threadIdx.x;
  if (tid < 4) sx[tid] = x[(size_t)bl*4 + tid];
  __syncthreads();
  float zv = beff[tid];
  zv = fmaf(sx[0], Weff[tid], zv);
  zv = fmaf(sx[1], Weff[904+tid], zv);
  zv = fmaf(sx[2], Weff[1808+tid], zv);
  zv = fmaf(sx[3], Weff[2712+tid], zv);
  float yv = y[(size_t)bl*384 + tid];
  float g = yv * (zv * sigmoidf_(zv));
  float ss = g*g;
  #pragma unroll
  for (int off=32; off>0; off>>=1) ss += __shfl_xor(ss, off);
  if ((tid&63)==0) sred[tid>>6] = ss;
  __syncthreads();
  if (tid==0){
    float t=0.f;
    #pragma unroll
    for (int i=0;i<6;i++) t += sred[i];
    srms = rsqrtf(t*(1.f/384.f) + 1e-5f);
  }
  __syncthreads();
  yn[(size_t)bl*384 + tid] = g * srms * norm_w[tid];
}

// ----- mlp2: m1 = relu(yn@Weff2 + b1) [K=384], m2 = relu(m1@W2+b2), mean -----
__global__ __launch_bounds__(256) void k_mlp2(
    const float* __restrict__ yn, const float* __restrict__ Weff2,
    const float* __restrict__ b1, const float* __restrict__ W2,
    const float* __restrict__ b2, float* __restrict__ macc){
  __shared__ __align__(16) float sW[384][32];   // 48 KB
  __shared__ __align__(16) float sm1[32][33];
  __shared__ __align__(16) float sW2[32][32];
  __shared__ __align__(16) float sm2[32][33];
  int tid = threadIdx.x;
  int tok0 = blockIdx.x*32;
  int b = tok0 >> 12;
  #pragma unroll
  for (int r=0;r<12;r++){
    int idx = tid + r*256;                 // float4 index over 3072
    int row = idx>>3, c4 = (idx&7)*4;
    *(float4*)&sW[row][c4] = *(const float4*)(Weff2 + (size_t)idx*4);
  }
  {
    int row = tid>>3, c4 = (tid&7)*4;
    *(float4*)&sW2[row][c4] = *(const float4*)(W2 + row*32 + c4);
  }
  __syncthreads();
  {
    int tok = tid>>3, j0 = (tid&7)*4;
    float a0[4];
    #pragma unroll
    for (int j=0;j<4;j++) a0[j] = b1[j0+j];
    const float* yrow = yn + (size_t)(tok0+tok)*384;
    for (int k4=0;k4<96;k4++){
      float4 a = *(const float4*)(yrow + k4*4);
      float w[4];
      *(float4*)w = *(float4*)&sW[k4*4+0][j0];
      #pragma unroll
      for (int j=0;j<4;j++) a0[j] = fmaf(a.x, w[j], a0[j]);
      *(float4*)w = *(float4*)&sW[k4*4+1][j0];
      #pragma unroll
      for (int j=0;j<4;j++) a0[j] = fmaf(a.y, w[j], a0[j]);
      *(float4*)w = *(float4*)&sW[k4*4+2][j0];
      #pragma unroll
      for (int j=0;j<4;j++) a0[j] = fmaf(a.z, w[j], a0[j]);
      *(float4*)w = *(float4*)&sW[k4*4+3][j0];
      #pragma unroll
      for (int j=0;j<4;j++) a0[j] = fmaf(a.w, w[j], a0[j]);
    }
    #pragma unroll
    for (int j=0;j<4;j++) sm1[tok][j0+j] = fmaxf(a0[j], 0.f);
  }
  __syncthreads();
  {
    int tok = tid>>3, j0 = (tid&7)*4;
    float a0[4];
    #pragma unroll
    for (int j=0;j<4;j++) a0[j] = b2[j0+j];
    #pragma unroll
    for (int kk=0;kk<32;kk++){
      float a = sm1[tok][kk];
      float w[4]; *(float4*)w = *(float4*)&sW2[kk][j0];
      #pragma unroll
      for (int j=0;j<4;j++) a0[j] = fmaf(a, w[j], a0[j]);
    }
    #pragma unroll
    for (int j=0;j<4;j++) sm2[tok][j0+j] = fmaxf(a0[j], 0.f);
  }
  __syncthreads();
  if (tid < 32){
    float t = 0.f;
    #pragma unroll
    for (int tok=0;tok<32;tok++) t += sm2[tok][tid];
    atomicAdd(&macc[b*32 + tid], t);
  }
}

// ----- final: angle[b] = mean_m @ Wo + bo -----
__global__ void k_final(const float* __restrict__ macc, const float* __restrict__ Wo,
                        const float* __restrict__ bo, float* __restrict__ out){
  int tid = threadIdx.x;
  if (tid < 4){
    float acc = bo[0];
    #pragma unroll
    for (int j=0;j<32;j++) acc = fmaf(macc[tid*32+j]*(1.f/4096.f), Wo[j], acc);
    out[tid] = acc;
  }
}

// ---------------------------------------------------------------------------
extern "C" void kernel_launch(void* const* d_in, const int* in_sizes, int n_in,
                              void* d_out, int out_size, void* d_ws, size_t ws_size,
                              hipStream_t stream){
  const float* x      = (const float*)d_in[0];
  const float* Wfc    = (const float*)d_in[1];
  const float* bfc    = (const float*)d_in[2];
  const float* W_in   = (const float*)d_in[3];
  const float* conv_w = (const float*)d_in[4];
  const float* conv_b = (const float*)d_in[5];
  const float* dt_bias= (const float*)d_in[6];
  const float* A_log  = (const float*)d_in[7];
  const float* Dparam = (const float*)d_in[8];
  const float* norm_w = (const float*)d_in[9];
  const float* W_out  = (const float*)d_in[10];
  const float* W1     = (const float*)d_in[11];
  const float* b1     = (const float*)d_in[12];
  const float* W2     = (const float*)d_in[13];
  const float* b2     = (const float*)d_in[14];
  const float* Wo     = (const float*)d_in[15];
  const float* bo     = (const float*)d_in[16];
  float* ws  = (float*)d_ws;
  float* out = (float*)d_out;

  float* Weff  = ws + OFF_W;          // 4x904
  float* beff  = ws + OFF_W + 4096;   // 904
  float* Weff2 = ws + OFF_W + 8192;   // 384x32
  float* yn    = ws + OFF_Z;
  float* Tb    = ws + OFF_T;
  float* xsb   = ws + OFF_XS;
  float* Bmb   = ws + OFF_BM;
  float* Cmb   = ws + OFF_CM;
  float* dtb   = ws + OFF_DT;
  float* lacb  = ws + OFF_LAC;
  float* Spb   = ws + OFF_SP;
  float* yb    = ws + OFF_Y;
  float* macc  = ws + OFF_MACC;

  hipMemsetAsync((void*)macc, 0, 128*sizeof(float), stream);

  k_prep1<<<dim3(4), dim3(256), 0, stream>>>(Wfc, bfc, W_in, Weff, beff);
  k_prep2<<<dim3(48), dim3(256), 0, stream>>>(W_out, W1, Weff2);
  k_ipc<<<dim3(BL), dim3(256), 0, stream>>>(x, Weff, beff, conv_w, conv_b,
                                            dt_bias, xsb, Bmb, Cmb, dtb);
  k_phase1<<<dim3(BH*NC), dim3(256), 0, stream>>>(dtb, Bmb, xsb, A_log, Tb, lacb);
  k_phase2p<<<dim3(BH,48), dim3(256), 0, stream>>>(Tb, lacb, Spb);
  k_phase3<<<dim3(BH*NC), dim3(256), 0, stream>>>(dtb, lacb, Bmb, Cmb, xsb, Spb, Dparam, yb);
  k_gate<<<dim3(BL), dim3(384), 0, stream>>>(x, Weff, beff, norm_w, yb, yn);
  k_mlp2<<<dim3(BL/32), dim3(256), 0, stream>>>(yn, Weff2, b1, W2, b2, macc);
  k_final<<<dim3(1), dim3(64), 0, stream>>>(macc, Wo, bo, out);
}

// Round 7
// 235.817 us; speedup vs baseline: 1.0815x; 1.0815x over previous
//
#include <hip/hip_runtime.h>
#include <math.h>

// ---------------------------------------------------------------------------
// MambaAnglePredictor — Round 7: phase3 rewritten on MFMA (split-bf16 3-term).
//   GM = C·B^T via mfma (natural layouts); mask/scale in C-layout; GM -> LDS
//   bf16 hi/lo; O = Y^T = X^T·GM^T + Sp^T·C^T (X/Sp staged transposed);
//   D·x + exp(la)·carry in epilogue. prep kernels merged (-2 dispatches).
// ---------------------------------------------------------------------------

#define BDIM 4
#define LDIM 4096
#define BL (BDIM*LDIM)      // 16384 tokens
#define QC 64               // chunk length
#define NC (LDIM/QC)        // 64 chunks
#define BH (BDIM*NH)        // 32
#define NH 8

// workspace offsets (floats)
#define OFF_W    0u          // Weff_in 4x904 @0, beff @4096, Weff2 @8192 (12288)
#define OFF_Z    3145728u    // yn (normalized y) fp32 16384*384
#define OFF_T    9437184u    // T 2048*3072
#define OFF_XS   17825792u   // 32*4096*48
#define OFF_BM   24117248u   // 16384*64
#define OFF_CM   25165824u   // 16384*64
#define OFF_DT   26214400u   // 32*4096
#define OFF_LAC  26345472u   // 2048*64
#define OFF_SP   26476544u   // 2048*3072
#define OFF_Y    32768000u   // 16384*384 fp32
#define OFF_MACC 39059456u   // 4*32

typedef unsigned short ushort_t;
typedef __attribute__((ext_vector_type(8))) short bf16x8;
typedef __attribute__((ext_vector_type(4))) float f32x4;

__device__ __forceinline__ float sigmoidf_(float x){ return 1.0f/(1.0f+__expf(-x)); }
__device__ __forceinline__ ushort_t f2bf(float x){
  unsigned int u = __float_as_uint(x);
  u += 0x7fffu + ((u>>16)&1u);
  return (ushort_t)(u>>16);
}
__device__ __forceinline__ float bf2f(ushort_t h){
  return __uint_as_float(((unsigned int)h)<<16);
}

// ----- prep (merged): Weff_in, beff, Weff2, macc zero -----
__global__ void k_prep(const float* __restrict__ Wfc, const float* __restrict__ bfc,
                       const float* __restrict__ W_in, const float* __restrict__ W_out,
                       const float* __restrict__ W1,
                       float* __restrict__ Weff, float* __restrict__ beff,
                       float* __restrict__ Weff2, float* __restrict__ macc){
  int blk = blockIdx.x, tid = threadIdx.x;
  if (blk < 4){
    int n = blk*256 + tid;
    if (n >= 904) return;
    float a0=0.f,a1=0.f,a2=0.f,a3=0.f,ab=0.f;
    for (int d=0; d<192; d++){
      float w = W_in[(size_t)d*904 + n];
      a0 = fmaf(Wfc[d], w, a0);
      a1 = fmaf(Wfc[192+d], w, a1);
      a2 = fmaf(Wfc[384+d], w, a2);
      a3 = fmaf(Wfc[576+d], w, a3);
      ab = fmaf(bfc[d], w, ab);
    }
    Weff[n] = a0; Weff[904+n] = a1; Weff[1808+n] = a2; Weff[2712+n] = a3;
    beff[n] = ab;
  } else {
    if (blk == 4 && tid < 128) macc[tid] = 0.f;
    int g = (blk-4)*256 + tid;   // 12288
    int i = g>>5, j = g&31;
    float a = 0.f;
    for (int d=0; d<192; d++) a = fmaf(W_out[(size_t)i*192+d], W1[d*32+j], a);
    Weff2[g] = a;
  }
}

// ----- ipc: fused in_proj(xBC cols)+conv+silu+dt. One block per token. -----
__global__ __launch_bounds__(256) void k_ipc(
    const float* __restrict__ x, const float* __restrict__ Weff,
    const float* __restrict__ beff, const float* __restrict__ conv_w,
    const float* __restrict__ conv_b, const float* __restrict__ dt_bias,
    float* __restrict__ xs, float* __restrict__ Bm, float* __restrict__ Cm,
    float* __restrict__ dtb){
  __shared__ float sx[4][4];
  int bl = blockIdx.x, tid = threadIdx.x;
  int l = bl & 4095, b = bl >> 12;
  if (tid < 16){
    int k = tid>>2, r = tid&3;
    int ll = l-3+k;
    sx[k][r] = (ll>=0) ? x[(size_t)(b*4096+ll)*4 + r] : 0.f;
  }
  __syncthreads();
  if (tid < 8){
    float raw = beff[896+tid];
    #pragma unroll
    for (int r=0;r<4;r++) raw = fmaf(sx[3][r], Weff[r*904+896+tid], raw);
    float xx = raw + dt_bias[tid];
    float dtv = (xx > 20.f) ? xx : log1pf(__expf(xx));
    dtb[(size_t)(b*8+tid)*4096 + l] = dtv;
  }
  #pragma unroll
  for (int half=0; half<2; half++){
    int c = tid + half*256;
    float w0 = Weff[384+c];
    float w1 = Weff[904+384+c];
    float w2 = Weff[1808+384+c];
    float w3 = Weff[2712+384+c];
    float bb = beff[384+c];
    float acc = conv_b[c];
    #pragma unroll
    for (int k=0;k<4;k++){
      int ll = l-3+k;
      float xv = bb;
      xv = fmaf(sx[k][0], w0, xv);
      xv = fmaf(sx[k][1], w1, xv);
      xv = fmaf(sx[k][2], w2, xv);
      xv = fmaf(sx[k][3], w3, xv);
      if (ll < 0) xv = 0.f;
      acc = fmaf(conv_w[k*512+c], xv, acc);
    }
    float v = acc * sigmoidf_(acc);
    if (c < 384){
      int hh = c / 48, p = c - hh*48;
      xs[(size_t)((b*8+hh)*4096 + l)*48 + p] = v;
    } else if (c < 448){
      Bm[(size_t)bl*64 + (c-384)] = v;
    } else {
      Cm[(size_t)bl*64 + (c-448)] = v;
    }
  }
}

// ----- phase1: per-chunk cumlog(dA), chunk state T_k = sum w_s B_s x_s^T -----
__global__ __launch_bounds__(256) void k_phase1(
    const float* __restrict__ dtbuf, const float* __restrict__ Bm,
    const float* __restrict__ xs, const float* __restrict__ A_log,
    float* __restrict__ T, float* __restrict__ lac){
  __shared__ float sdt[64], sla[64], sw[64];
  __shared__ __align__(16) float sBW[64][64];
  __shared__ __align__(16) float sX[64][48];
  int tid = threadIdx.x, blk = blockIdx.x;
  int bh = blk >> 6, k = blk & 63;
  int b = bh >> 3, hh = bh & 7;
  int t0 = k*64;
  if (tid < 64) sdt[tid] = dtbuf[(size_t)bh*4096 + t0 + tid];
  __syncthreads();
  if (tid == 0){
    float eA = __expf(A_log[hh]);
    float cum = 0.f;
    for (int i=0;i<64;i++){ cum -= sdt[i]*eA; sla[i] = cum; }
  }
  __syncthreads();
  if (tid < 64){
    sw[tid] = __expf(sla[63]-sla[tid])*sdt[tid];
    lac[(size_t)blk*64 + tid] = sla[tid];
  }
  __syncthreads();
  {
    int s = tid>>2, n0 = (tid&3)*16;
    float wsc = sw[s];
    const float* src = Bm + (size_t)(b*4096 + t0 + s)*64 + n0;
    #pragma unroll
    for (int q=0;q<4;q++){
      float4 v = *(const float4*)(src + q*4);
      v.x*=wsc; v.y*=wsc; v.z*=wsc; v.w*=wsc;
      *(float4*)&sBW[s][n0+q*4] = v;
    }
    int p0 = (tid&3)*12;
    const float* xsrc = xs + (size_t)(bh*4096 + t0 + s)*48 + p0;
    #pragma unroll
    for (int q=0;q<3;q++) *(float4*)&sX[s][p0+q*4] = *(const float4*)(xsrc + q*4);
  }
  __syncthreads();
  if (tid < 192){
    int n0 = (tid/12)*4, p0 = (tid%12)*4;
    float acc[4][4];
    #pragma unroll
    for (int i=0;i<4;i++)
      #pragma unroll
      for (int j=0;j<4;j++) acc[i][j]=0.f;
    for (int s=0;s<64;s++){
      float bw[4], xv[4];
      *(float4*)bw = *(float4*)&sBW[s][n0];
      *(float4*)xv = *(float4*)&sX[s][p0];
      #pragma unroll
      for (int i=0;i<4;i++)
        #pragma unroll
        for (int j=0;j<4;j++) acc[i][j] = fmaf(bw[i], xv[j], acc[i][j]);
    }
    float* dst = T + (size_t)blk*3072;
    #pragma unroll
    for (int i=0;i<4;i++){
      float4 o; o.x=acc[i][0]; o.y=acc[i][1]; o.z=acc[i][2]; o.w=acc[i][3];
      *(float4*)(dst + (n0+i)*48 + p0) = o;
    }
  }
}

// ----- phase2p: Sp[k] = sum_{j<k} W[k][j] T[j] (parallel triangular) -----
__global__ __launch_bounds__(256) void k_phase2p(
    const float* __restrict__ T, const float* __restrict__ lac, float* __restrict__ Sp){
  __shared__ __align__(16) float sT[64*64];
  __shared__ __align__(16) float sW[64][68];
  __shared__ float sc[64];
  int tid = threadIdx.x;
  int bh = blockIdx.x, es = blockIdx.y;
  #pragma unroll
  for (int r=0;r<4;r++){
    int idx = tid + r*256;
    int row = idx>>4, c4 = (idx&15)*4;
    *(float4*)&sT[row*64 + c4] = *(const float4*)(T + (size_t)(bh*64+row)*3072 + es*64 + c4);
  }
  if (tid < 64) sc[tid] = __expf(lac[(size_t)(bh*64+tid)*64 + 63]);
  __syncthreads();
  if (tid < 64){
    int k = tid;
    float w = 1.f;
    for (int j=63; j>=0; --j){
      bool a = (j < k);
      sW[j][k] = a ? w : 0.f;
      if (a) w *= sc[j];
    }
  }
  __syncthreads();
  int k0 = (tid>>4)*4, e0 = (tid&15)*4;
  float acc[4][4];
  #pragma unroll
  for (int i=0;i<4;i++)
    #pragma unroll
    for (int j=0;j<4;j++) acc[i][j]=0.f;
  int jmax = k0+2; if (jmax > 62) jmax = 62;
  for (int j=0; j<=jmax; ++j){
    float wv[4], tv[4];
    *(float4*)wv = *(float4*)&sW[j][k0];
    *(float4*)tv = *(float4*)&sT[j*64 + e0];
    #pragma unroll
    for (int i=0;i<4;i++)
      #pragma unroll
      for (int e=0;e<4;e++) acc[i][e] = fmaf(wv[i], tv[e], acc[i][e]);
  }
  #pragma unroll
  for (int i=0;i<4;i++){
    float4 o; o.x=acc[i][0]; o.y=acc[i][1]; o.z=acc[i][2]; o.w=acc[i][3];
    *(float4*)(Sp + (size_t)(bh*64+k0+i)*3072 + es*64 + e0) = o;
  }
}

// ----- phase3 (MFMA): per (bh, chunk):
//   GM(i,s) = mask( C·B^T ) * exp(la_i-la_s)*dt_s   [mfma, C-layout scale]
//   O(p,i)  = X^T·GM^T + exp(la_i)*(Sp^T·C^T) + D*x^T
// LDS: C,B(->GM),X^T,Sp^T bf16 hi/lo, stride 72 shorts. 65 KB -> 2 blk/CU.
__global__ __launch_bounds__(256, 2) void k_phase3(
    const float* __restrict__ dtbuf, const float* __restrict__ lac,
    const float* __restrict__ Bm, const float* __restrict__ Cm,
    const float* __restrict__ xs, const float* __restrict__ Sp,
    const float* __restrict__ Dparam, float* __restrict__ y){
  __shared__ __align__(16) ushort_t sCh[64*72], sCl[64*72];   // C[i][n]
  __shared__ __align__(16) ushort_t sBh[64*72], sBl[64*72];   // B[s][n] -> GM[i][s]
  __shared__ __align__(16) ushort_t sXh[48*72], sXl[48*72];   // X^T[p][s]
  __shared__ __align__(16) ushort_t sPh[48*72], sPl[48*72];   // Sp^T[p][n]
  __shared__ float sla[64], sdt[64];
  int tid = threadIdx.x, blk = blockIdx.x;
  int bh = blk>>6, k = blk&63, b = bh>>3, hh = bh&7, t0 = k*64;
  int w = tid>>6, lane = tid&63, l15 = lane&15, quad = lane>>4;

  if (tid < 64){
    sdt[tid] = dtbuf[(size_t)bh*4096 + t0 + tid];
    sla[tid] = lac[(size_t)blk*64 + tid];
  }
  // ---- stage C, B (row-major, bf16 hi/lo) ----
  {
    int row = tid>>2, ng = (tid&3)*16;
    const float* csrc = Cm + (size_t)(b*4096+t0+row)*64 + ng;
    const float* bsrc = Bm + (size_t)(b*4096+t0+row)*64 + ng;
    #pragma unroll
    for (int q=0;q<4;q++){
      float4 cv = *(const float4*)(csrc + q*4);
      float4 bv = *(const float4*)(bsrc + q*4);
      ushort4 chv, clv, bhv, blv;
      chv.x=f2bf(cv.x); chv.y=f2bf(cv.y); chv.z=f2bf(cv.z); chv.w=f2bf(cv.w);
      clv.x=f2bf(cv.x-bf2f(chv.x)); clv.y=f2bf(cv.y-bf2f(chv.y));
      clv.z=f2bf(cv.z-bf2f(chv.z)); clv.w=f2bf(cv.w-bf2f(chv.w));
      bhv.x=f2bf(bv.x); bhv.y=f2bf(bv.y); bhv.z=f2bf(bv.z); bhv.w=f2bf(bv.w);
      blv.x=f2bf(bv.x-bf2f(bhv.x)); blv.y=f2bf(bv.y-bf2f(bhv.y));
      blv.z=f2bf(bv.z-bf2f(bhv.z)); blv.w=f2bf(bv.w-bf2f(bhv.w));
      int o = row*72 + ng + q*4;
      *(ushort4*)&sCh[o] = chv; *(ushort4*)&sCl[o] = clv;
      *(ushort4*)&sBh[o] = bhv; *(ushort4*)&sBl[o] = blv;
    }
  }
  // ---- stage X^T, Sp^T (transposed, packed pair writes) ----
  {
    int n2 = (tid>>3)*2;          // 0,2,...,62
    int p0 = (tid&7)*6;           // 0..42
    const float* x0 = xs + (size_t)(bh*4096+t0+n2)*48 + p0;
    const float* x1 = x0 + 48;
    const float* s0 = Sp + (size_t)blk*3072 + n2*48 + p0;
    const float* s1 = s0 + 48;
    #pragma unroll
    for (int c=0;c<6;c++){
      float a0 = x0[c], a1 = x1[c];
      ushort_t h0 = f2bf(a0), h1 = f2bf(a1);
      ushort_t l0 = f2bf(a0-bf2f(h0)), l1 = f2bf(a1-bf2f(h1));
      int o = (p0+c)*72 + n2;
      *(unsigned int*)&sXh[o] = (unsigned int)h0 | ((unsigned int)h1<<16);
      *(unsigned int*)&sXl[o] = (unsigned int)l0 | ((unsigned int)l1<<16);
      float q0 = s0[c], q1 = s1[c];
      ushort_t ph0 = f2bf(q0), ph1 = f2bf(q1);
      ushort_t pl0 = f2bf(q0-bf2f(ph0)), pl1 = f2bf(q1-bf2f(ph1));
      *(unsigned int*)&sPh[o] = (unsigned int)ph0 | ((unsigned int)ph1<<16);
      *(unsigned int*)&sPl[o] = (unsigned int)pl0 | ((unsigned int)pl1<<16);
    }
  }
  __syncthreads();

  // ---- GM mfma: wave w owns i-band w, s-tiles 0..w ----
  f32x4 gacc[4];
  #pragma unroll
  for (int t=0;t<4;t++) gacc[t] = (f32x4)(0.f);
  {
    bf16x8 cah[2], cal[2];
    #pragma unroll
    for (int ks=0;ks<2;ks++){
      int ao = (w*16+l15)*72 + ks*32 + quad*8;
      cah[ks] = *(bf16x8*)&sCh[ao];
      cal[ks] = *(bf16x8*)&sCl[ao];
    }
    for (int bs=0; bs<=w; ++bs){
      #pragma unroll
      for (int ks=0;ks<2;ks++){
        int bo = (bs*16+l15)*72 + ks*32 + quad*8;
        bf16x8 bhf = *(bf16x8*)&sBh[bo];
        bf16x8 blf = *(bf16x8*)&sBl[bo];
        gacc[bs] = __builtin_amdgcn_mfma_f32_16x16x32_bf16(cah[ks], bhf, gacc[bs], 0,0,0);
        gacc[bs] = __builtin_amdgcn_mfma_f32_16x16x32_bf16(cah[ks], blf, gacc[bs], 0,0,0);
        gacc[bs] = __builtin_amdgcn_mfma_f32_16x16x32_bf16(cal[ks], bhf, gacc[bs], 0,0,0);
      }
    }
  }
  __syncthreads();   // sB reads done -> safe to overwrite with GM

  // ---- scale/mask, write GM bf16 hi/lo into sBh/sBl; zero needed tiles ----
  for (int bs=0; bs<=w; ++bs){
    #pragma unroll
    for (int r=0;r<4;r++){
      int i = w*16 + quad*4 + r;
      int s = bs*16 + l15;
      float v = 0.f;
      if (s <= i) v = gacc[bs][r] * __expf(sla[i]-sla[s]) * sdt[s];
      ushort_t hi = f2bf(v);
      sBh[i*72+s] = hi;
      sBl[i*72+s] = f2bf(v - bf2f(hi));
    }
  }
  if (w==0){
    #pragma unroll
    for (int r=0;r<4;r++){ sBh[(quad*4+r)*72 + 16+l15] = 0; sBl[(quad*4+r)*72 + 16+l15] = 0; }
  }
  if (w==2){
    #pragma unroll
    for (int r=0;r<4;r++){ sBh[(32+quad*4+r)*72 + 48+l15] = 0; sBl[(32+quad*4+r)*72 + 48+l15] = 0; }
  }
  __syncthreads();

  // ---- O = X^T·GM^T (intra) + Sp^T·C^T (carry); wave w owns i-tile w ----
  f32x4 accI[3], accA[3];
  #pragma unroll
  for (int t=0;t<3;t++){ accI[t] = (f32x4)(0.f); accA[t] = (f32x4)(0.f); }
  int nks = (w>=2) ? 2 : 1;
  for (int ks=0; ks<nks; ++ks){
    int go = (w*16+l15)*72 + ks*32 + quad*8;
    bf16x8 gbh = *(bf16x8*)&sBh[go];
    bf16x8 gbl = *(bf16x8*)&sBl[go];
    #pragma unroll
    for (int pt=0;pt<3;pt++){
      int xo = (pt*16+l15)*72 + ks*32 + quad*8;
      bf16x8 xah = *(bf16x8*)&sXh[xo];
      bf16x8 xal = *(bf16x8*)&sXl[xo];
      accI[pt] = __builtin_amdgcn_mfma_f32_16x16x32_bf16(xah, gbh, accI[pt], 0,0,0);
      accI[pt] = __builtin_amdgcn_mfma_f32_16x16x32_bf16(xah, gbl, accI[pt], 0,0,0);
      accI[pt] = __builtin_amdgcn_mfma_f32_16x16x32_bf16(xal, gbh, accI[pt], 0,0,0);
    }
  }
  #pragma unroll
  for (int ks=0; ks<2; ++ks){
    int co = (w*16+l15)*72 + ks*32 + quad*8;
    bf16x8 cbh = *(bf16x8*)&sCh[co];
    bf16x8 cbl = *(bf16x8*)&sCl[co];
    #pragma unroll
    for (int pt=0;pt<3;pt++){
      int po = (pt*16+l15)*72 + ks*32 + quad*8;
      bf16x8 pah = *(bf16x8*)&sPh[po];
      bf16x8 pal = *(bf16x8*)&sPl[po];
      accA[pt] = __builtin_amdgcn_mfma_f32_16x16x32_bf16(pah, cbh, accA[pt], 0,0,0);
      accA[pt] = __builtin_amdgcn_mfma_f32_16x16x32_bf16(pah, cbl, accA[pt], 0,0,0);
      accA[pt] = __builtin_amdgcn_mfma_f32_16x16x32_bf16(pal, cbh, accA[pt], 0,0,0);
    }
  }
  // ---- epilogue: Y[i][p] = accI + exp(la_i)*accA + D*x ----
  {
    int i = w*16 + l15;
    float eli = __expf(sla[i]);
    float Dh = Dparam[hh];
    float* ybase = y + (size_t)(b*4096+t0+i)*384 + hh*48;
    #pragma unroll
    for (int pt=0;pt<3;pt++)
      #pragma unroll
      for (int r=0;r<4;r++){
        int p = pt*16 + quad*4 + r;
        float xf = bf2f(sXh[p*72 + i]) + bf2f(sXl[p*72 + i]);
        ybase[p] = accI[pt][r] + eli*accA[pt][r] + Dh*xf;
      }
  }
}

// ----- gate: z recomputed from x (K=4); g=y*silu(z); RMSNorm; write yn -----
__global__ __launch_bounds__(384) void k_gate(
    const float* __restrict__ x, const float* __restrict__ Weff,
    const float* __restrict__ beff, const float* __restrict__ norm_w,
    const float* __restrict__ y, float* __restrict__ yn){
  __shared__ float sred[6];
  __shared__ float srms;
  __shared__ float sx[4];
  int bl = blockIdx.x, tid = threadIdx.x;
  if (tid < 4) sx[tid] = x[(size_t)bl*4 + tid];
  __syncthreads();
  float zv = beff[tid];
  zv = fmaf(sx[0], Weff[tid], zv);
  zv = fmaf(sx[1], Weff[904+tid], zv);
  zv = fmaf(sx[2], Weff[1808+tid], zv);
  zv = fmaf(sx[3], Weff[2712+tid], zv);
  float yv = y[(size_t)bl*384 + tid];
  float g = yv * (zv * sigmoidf_(zv));
  float ss = g*g;
  #pragma unroll
  for (int off=32; off>0; off>>=1) ss += __shfl_xor(ss, off);
  if ((tid&63)==0) sred[tid>>6] = ss;
  __syncthreads();
  if (tid==0){
    float t=0.f;
    #pragma unroll
    for (int i=0;i<6;i++) t += sred[i];
    srms = rsqrtf(t*(1.f/384.f) + 1e-5f);
  }
  __syncthreads();
  yn[(size_t)bl*384 + tid] = g * srms * norm_w[tid];
}

// ----- mlp2: m1 = relu(yn@Weff2 + b1) [K=384], m2 = relu(m1@W2+b2), mean -----
__global__ __launch_bounds__(256) void k_mlp2(
    const float* __restrict__ yn, const float* __restrict__ Weff2,
    const float* __restrict__ b1, const float* __restrict__ W2,
    const float* __restrict__ b2, float* __restrict__ macc){
  __shared__ __align__(16) float sW[384][32];
  __shared__ __align__(16) float sm1[32][33];
  __shared__ __align__(16) float sW2[32][32];
  __shared__ __align__(16) float sm2[32][33];
  int tid = threadIdx.x;
  int tok0 = blockIdx.x*32;
  int b = tok0 >> 12;
  #pragma unroll
  for (int r=0;r<12;r++){
    int idx = tid + r*256;
    int row = idx>>3, c4 = (idx&7)*4;
    *(float4*)&sW[row][c4] = *(const float4*)(Weff2 + (size_t)idx*4);
  }
  {
    int row = tid>>3, c4 = (tid&7)*4;
    *(float4*)&sW2[row][c4] = *(const float4*)(W2 + row*32 + c4);
  }
  __syncthreads();
  {
    int tok = tid>>3, j0 = (tid&7)*4;
    float a0[4];
    #pragma unroll
    for (int j=0;j<4;j++) a0[j] = b1[j0+j];
    const float* yrow = yn + (size_t)(tok0+tok)*384;
    for (int k4=0;k4<96;k4++){
      float4 a = *(const float4*)(yrow + k4*4);
      float w[4];
      *(float4*)w = *(float4*)&sW[k4*4+0][j0];
      #pragma unroll
      for (int j=0;j<4;j++) a0[j] = fmaf(a.x, w[j], a0[j]);
      *(float4*)w = *(float4*)&sW[k4*4+1][j0];
      #pragma unroll
      for (int j=0;j<4;j++) a0[j] = fmaf(a.y, w[j], a0[j]);
      *(float4*)w = *(float4*)&sW[k4*4+2][j0];
      #pragma unroll
      for (int j=0;j<4;j++) a0[j] = fmaf(a.z, w[j], a0[j]);
      *(float4*)w = *(float4*)&sW[k4*4+3][j0];
      #pragma unroll
      for (int j=0;j<4;j++) a0[j] = fmaf(a.w, w[j], a0[j]);
    }
    #pragma unroll
    for (int j=0;j<4;j++) sm1[tok][j0+j] = fmaxf(a0[j], 0.f);
  }
  __syncthreads();
  {
    int tok = tid>>3, j0 = (tid&7)*4;
    float a0[4];
    #pragma unroll
    for (int j=0;j<4;j++) a0[j] = b2[j0+j];
    #pragma unroll
    for (int kk=0;kk<32;kk++){
      float a = sm1[tok][kk];
      float w[4]; *(float4*)w = *(float4*)&sW2[kk][j0];
      #pragma unroll
      for (int j=0;j<4;j++) a0[j] = fmaf(a, w[j], a0[j]);
    }
    #pragma unroll
    for (int j=0;j<4;j++) sm2[tok][j0+j] = fmaxf(a0[j], 0.f);
  }
  __syncthreads();
  if (tid < 32){
    float t = 0.f;
    #pragma unroll
    for (int tok=0;tok<32;tok++) t += sm2[tok][tid];
    atomicAdd(&macc[b*32 + tid], t);
  }
}

// ----- final: angle[b] = mean_m @ Wo + bo -----
__global__ void k_final(const float* __restrict__ macc, const float* __restrict__ Wo,
                        const float* __restrict__ bo, float* __restrict__ out){
  int tid = threadIdx.x;
  if (tid < 4){
    float acc = bo[0];
    #pragma unroll
    for (int j=0;j<32;j++) acc = fmaf(macc[tid*32+j]*(1.f/4096.f), Wo[j], acc);
    out[tid] = acc;
  }
}

// ---------------------------------------------------------------------------
extern "C" void kernel_launch(void* const* d_in, const int* in_sizes, int n_in,
                              void* d_out, int out_size, void* d_ws, size_t ws_size,
                              hipStream_t stream){
  const float* x      = (const float*)d_in[0];
  const float* Wfc    = (const float*)d_in[1];
  const float* bfc    = (const float*)d_in[2];
  const float* W_in   = (const float*)d_in[3];
  const float* conv_w = (const float*)d_in[4];
  const float* conv_b = (const float*)d_in[5];
  const float* dt_bias= (const float*)d_in[6];
  const float* A_log  = (const float*)d_in[7];
  const float* Dparam = (const float*)d_in[8];
  const float* norm_w = (const float*)d_in[9];
  const float* W_out  = (const float*)d_in[10];
  const float* W1     = (const float*)d_in[11];
  const float* b1     = (const float*)d_in[12];
  const float* W2     = (const float*)d_in[13];
  const float* b2     = (const float*)d_in[14];
  const float* Wo     = (const float*)d_in[15];
  const float* bo     = (const float*)d_in[16];
  float* ws  = (float*)d_ws;
  float* out = (float*)d_out;

  float* Weff  = ws + OFF_W;
  float* beff  = ws + OFF_W + 4096;
  float* Weff2 = ws + OFF_W + 8192;
  float* yn    = ws + OFF_Z;
  float* Tb    = ws + OFF_T;
  float* xsb   = ws + OFF_XS;
  float* Bmb   = ws + OFF_BM;
  float* Cmb   = ws + OFF_CM;
  float* dtb   = ws + OFF_DT;
  float* lacb  = ws + OFF_LAC;
  float* Spb   = ws + OFF_SP;
  float* yb    = ws + OFF_Y;
  float* macc  = ws + OFF_MACC;

  k_prep<<<dim3(52), dim3(256), 0, stream>>>(Wfc, bfc, W_in, W_out, W1,
                                             Weff, beff, Weff2, macc);
  k_ipc<<<dim3(BL), dim3(256), 0, stream>>>(x, Weff, beff, conv_w, conv_b,
                                            dt_bias, xsb, Bmb, Cmb, dtb);
  k_phase1<<<dim3(BH*NC), dim3(256), 0, stream>>>(dtb, Bmb, xsb, A_log, Tb, lacb);
  k_phase2p<<<dim3(BH,48), dim3(256), 0, stream>>>(Tb, lacb, Spb);
  k_phase3<<<dim3(BH*NC), dim3(256), 0, stream>>>(dtb, lacb, Bmb, Cmb, xsb, Spb, Dparam, yb);
  k_gate<<<dim3(BL), dim3(384), 0, stream>>>(x, Weff, beff, norm_w, yb, yn);
  k_mlp2<<<dim3(BL/32), dim3(256), 0, stream>>>(yn, Weff2, b1, W2, b2, macc);
  k_final<<<dim3(1), dim3(64), 0, stream>>>(macc, Wo, bo, out);
}

// Round 8
// 230.526 us; speedup vs baseline: 1.1063x; 1.0230x over previous
//
#include <hip/hip_runtime.h>
#include <math.h>

// ---------------------------------------------------------------------------
// MambaAnglePredictor — Round 8:
//   phase1 -> MFMA (split-bf16, T stored transposed [p][n])
//   phase3 Sp staging now direct (coalesced) thanks to [p][n] layout
//   mlp2: 2 tokens/thread (halve LDS instruction count)
// ---------------------------------------------------------------------------

#define BDIM 4
#define LDIM 4096
#define BL (BDIM*LDIM)      // 16384 tokens
#define QC 64               // chunk length
#define NC (LDIM/QC)        // 64 chunks
#define BH (BDIM*NH)        // 32
#define NH 8

// workspace offsets (floats)
#define OFF_W    0u          // Weff_in 4x904 @0, beff @4096, Weff2 @8192
#define OFF_Z    3145728u    // yn fp32 16384*384
#define OFF_T    9437184u    // T 2048*3072  (layout [p][n] per chunk)
#define OFF_XS   17825792u   // 32*4096*48
#define OFF_BM   24117248u   // 16384*64
#define OFF_CM   25165824u   // 16384*64
#define OFF_DT   26214400u   // 32*4096
#define OFF_LAC  26345472u   // 2048*64
#define OFF_SP   26476544u   // 2048*3072 (layout [p][n] per chunk)
#define OFF_Y    32768000u   // 16384*384 fp32
#define OFF_MACC 39059456u   // 4*32

typedef unsigned short ushort_t;
typedef __attribute__((ext_vector_type(8))) short bf16x8;
typedef __attribute__((ext_vector_type(4))) float f32x4;

__device__ __forceinline__ float sigmoidf_(float x){ return 1.0f/(1.0f+__expf(-x)); }
__device__ __forceinline__ ushort_t f2bf(float x){
  unsigned int u = __float_as_uint(x);
  u += 0x7fffu + ((u>>16)&1u);
  return (ushort_t)(u>>16);
}
__device__ __forceinline__ float bf2f(ushort_t h){
  return __uint_as_float(((unsigned int)h)<<16);
}

// ----- prep (merged): Weff_in, beff, Weff2, macc zero -----
__global__ void k_prep(const float* __restrict__ Wfc, const float* __restrict__ bfc,
                       const float* __restrict__ W_in, const float* __restrict__ W_out,
                       const float* __restrict__ W1,
                       float* __restrict__ Weff, float* __restrict__ beff,
                       float* __restrict__ Weff2, float* __restrict__ macc){
  int blk = blockIdx.x, tid = threadIdx.x;
  if (blk < 4){
    int n = blk*256 + tid;
    if (n >= 904) return;
    float a0=0.f,a1=0.f,a2=0.f,a3=0.f,ab=0.f;
    for (int d=0; d<192; d++){
      float w = W_in[(size_t)d*904 + n];
      a0 = fmaf(Wfc[d], w, a0);
      a1 = fmaf(Wfc[192+d], w, a1);
      a2 = fmaf(Wfc[384+d], w, a2);
      a3 = fmaf(Wfc[576+d], w, a3);
      ab = fmaf(bfc[d], w, ab);
    }
    Weff[n] = a0; Weff[904+n] = a1; Weff[1808+n] = a2; Weff[2712+n] = a3;
    beff[n] = ab;
  } else {
    if (blk == 4 && tid < 128) macc[tid] = 0.f;
    int g = (blk-4)*256 + tid;   // 12288
    int i = g>>5, j = g&31;
    float a = 0.f;
    for (int d=0; d<192; d++) a = fmaf(W_out[(size_t)i*192+d], W1[d*32+j], a);
    Weff2[g] = a;
  }
}

// ----- ipc: fused in_proj(xBC cols)+conv+silu+dt. One block per token. -----
__global__ __launch_bounds__(256) void k_ipc(
    const float* __restrict__ x, const float* __restrict__ Weff,
    const float* __restrict__ beff, const float* __restrict__ conv_w,
    const float* __restrict__ conv_b, const float* __restrict__ dt_bias,
    float* __restrict__ xs, float* __restrict__ Bm, float* __restrict__ Cm,
    float* __restrict__ dtb){
  __shared__ float sx[4][4];
  int bl = blockIdx.x, tid = threadIdx.x;
  int l = bl & 4095, b = bl >> 12;
  if (tid < 16){
    int k = tid>>2, r = tid&3;
    int ll = l-3+k;
    sx[k][r] = (ll>=0) ? x[(size_t)(b*4096+ll)*4 + r] : 0.f;
  }
  __syncthreads();
  if (tid < 8){
    float raw = beff[896+tid];
    #pragma unroll
    for (int r=0;r<4;r++) raw = fmaf(sx[3][r], Weff[r*904+896+tid], raw);
    float xx = raw + dt_bias[tid];
    float dtv = (xx > 20.f) ? xx : log1pf(__expf(xx));
    dtb[(size_t)(b*8+tid)*4096 + l] = dtv;
  }
  #pragma unroll
  for (int half=0; half<2; half++){
    int c = tid + half*256;
    float w0 = Weff[384+c];
    float w1 = Weff[904+384+c];
    float w2 = Weff[1808+384+c];
    float w3 = Weff[2712+384+c];
    float bb = beff[384+c];
    float acc = conv_b[c];
    #pragma unroll
    for (int k=0;k<4;k++){
      int ll = l-3+k;
      float xv = bb;
      xv = fmaf(sx[k][0], w0, xv);
      xv = fmaf(sx[k][1], w1, xv);
      xv = fmaf(sx[k][2], w2, xv);
      xv = fmaf(sx[k][3], w3, xv);
      if (ll < 0) xv = 0.f;
      acc = fmaf(conv_w[k*512+c], xv, acc);
    }
    float v = acc * sigmoidf_(acc);
    if (c < 384){
      int hh = c / 48, p = c - hh*48;
      xs[(size_t)((b*8+hh)*4096 + l)*48 + p] = v;
    } else if (c < 448){
      Bm[(size_t)bl*64 + (c-384)] = v;
    } else {
      Cm[(size_t)bl*64 + (c-448)] = v;
    }
  }
}

// ----- phase1 (MFMA): T^T[p][n] = X^T(48x64) · Bw^T(64x64)^T  per chunk -----
// A-frag = X^T[p][s] (pack-pair transposed), B-frag = Bw^T[n][s] (ditto).
// Wave w owns n-tile w (all 3 p-tiles). Also computes cumlog la, writes lac.
__global__ __launch_bounds__(256) void k_phase1(
    const float* __restrict__ dtbuf, const float* __restrict__ Bm,
    const float* __restrict__ xs, const float* __restrict__ A_log,
    float* __restrict__ T, float* __restrict__ lac){
  __shared__ __align__(16) ushort_t sBh[64*72], sBl[64*72];   // Bw^T [n][s]
  __shared__ __align__(16) ushort_t sXh[48*72], sXl[48*72];   // X^T [p][s]
  __shared__ float sdt[64], sla[64], sw[64];
  int tid = threadIdx.x, blk = blockIdx.x;
  int bh = blk >> 6, k = blk & 63;
  int b = bh >> 3, hh = bh & 7;
  int t0 = k*64;
  int w = tid>>6, lane = tid&63, l15 = lane&15, quad = lane>>4;

  if (tid < 64) sdt[tid] = dtbuf[(size_t)bh*4096 + t0 + tid];
  __syncthreads();
  if (tid == 0){
    float eA = __expf(A_log[hh]);
    float cum = 0.f;
    for (int i=0;i<64;i++){ cum -= sdt[i]*eA; sla[i] = cum; }
  }
  __syncthreads();
  if (tid < 64){
    sw[tid] = __expf(sla[63]-sla[tid])*sdt[tid];
    lac[(size_t)blk*64 + tid] = sla[tid];
  }
  __syncthreads();
  // stage Bw^T [n][s] hi/lo (pack-pair transpose, scaled by sw)
  {
    int s2 = (tid&31)*2, ng = (tid>>5)*8;
    const float* b0 = Bm + (size_t)(b*4096+t0+s2)*64 + ng;
    const float* b1 = b0 + 64;
    float w0 = sw[s2], w1 = sw[s2+1];
    float4 a0 = *(const float4*)b0, a1 = *(const float4*)(b0+4);
    float4 c0 = *(const float4*)b1, c1 = *(const float4*)(b1+4);
    float v0[8] = {a0.x,a0.y,a0.z,a0.w,a1.x,a1.y,a1.z,a1.w};
    float v1[8] = {c0.x,c0.y,c0.z,c0.w,c1.x,c1.y,c1.z,c1.w};
    #pragma unroll
    for (int c=0;c<8;c++){
      float f0 = v0[c]*w0, f1 = v1[c]*w1;
      ushort_t h0 = f2bf(f0), h1 = f2bf(f1);
      ushort_t l0 = f2bf(f0-bf2f(h0)), l1 = f2bf(f1-bf2f(h1));
      int o = (ng+c)*72 + s2;
      *(unsigned int*)&sBh[o] = (unsigned int)h0 | ((unsigned int)h1<<16);
      *(unsigned int*)&sBl[o] = (unsigned int)l0 | ((unsigned int)l1<<16);
    }
  }
  // stage X^T [p][s] hi/lo (pack-pair transpose)
  {
    int s2 = (tid>>3)*2, p0 = (tid&7)*6;
    const float* x0 = xs + (size_t)(bh*4096+t0+s2)*48 + p0;
    const float* x1 = x0 + 48;
    #pragma unroll
    for (int c=0;c<6;c++){
      float a0 = x0[c], a1 = x1[c];
      ushort_t h0 = f2bf(a0), h1 = f2bf(a1);
      ushort_t l0 = f2bf(a0-bf2f(h0)), l1 = f2bf(a1-bf2f(h1));
      int o = (p0+c)*72 + s2;
      *(unsigned int*)&sXh[o] = (unsigned int)h0 | ((unsigned int)h1<<16);
      *(unsigned int*)&sXl[o] = (unsigned int)l0 | ((unsigned int)l1<<16);
    }
  }
  __syncthreads();
  // MFMA: wave w -> n-tile w; 3 p-tiles; K=64 (2 ksteps), 3-term split
  f32x4 acc[3];
  #pragma unroll
  for (int t=0;t<3;t++) acc[t] = (f32x4)(0.f);
  #pragma unroll
  for (int ks=0;ks<2;ks++){
    int bo = (w*16+l15)*72 + ks*32 + quad*8;
    bf16x8 bbh = *(bf16x8*)&sBh[bo];
    bf16x8 bbl = *(bf16x8*)&sBl[bo];
    #pragma unroll
    for (int pt=0;pt<3;pt++){
      int xo = (pt*16+l15)*72 + ks*32 + quad*8;
      bf16x8 xah = *(bf16x8*)&sXh[xo];
      bf16x8 xal = *(bf16x8*)&sXl[xo];
      acc[pt] = __builtin_amdgcn_mfma_f32_16x16x32_bf16(xah, bbh, acc[pt], 0,0,0);
      acc[pt] = __builtin_amdgcn_mfma_f32_16x16x32_bf16(xah, bbl, acc[pt], 0,0,0);
      acc[pt] = __builtin_amdgcn_mfma_f32_16x16x32_bf16(xal, bbh, acc[pt], 0,0,0);
    }
  }
  // write T^T: row p = pt*16+quad*4+r, col n = w*16+l15
  {
    float* dst = T + (size_t)blk*3072;
    #pragma unroll
    for (int pt=0;pt<3;pt++)
      #pragma unroll
      for (int r=0;r<4;r++)
        dst[(pt*16+quad*4+r)*64 + w*16 + l15] = acc[pt][r];
  }
}

// ----- phase2p: Sp[k] = sum_{j<k} W[k][j] T[j] (parallel triangular, flat e) -----
__global__ __launch_bounds__(256) void k_phase2p(
    const float* __restrict__ T, const float* __restrict__ lac, float* __restrict__ Sp){
  __shared__ __align__(16) float sT[64*64];
  __shared__ __align__(16) float sW[64][68];
  __shared__ float sc[64];
  int tid = threadIdx.x;
  int bh = blockIdx.x, es = blockIdx.y;
  #pragma unroll
  for (int r=0;r<4;r++){
    int idx = tid + r*256;
    int row = idx>>4, c4 = (idx&15)*4;
    *(float4*)&sT[row*64 + c4] = *(const float4*)(T + (size_t)(bh*64+row)*3072 + es*64 + c4);
  }
  if (tid < 64) sc[tid] = __expf(lac[(size_t)(bh*64+tid)*64 + 63]);
  __syncthreads();
  if (tid < 64){
    int k = tid;
    float w = 1.f;
    for (int j=63; j>=0; --j){
      bool a = (j < k);
      sW[j][k] = a ? w : 0.f;
      if (a) w *= sc[j];
    }
  }
  __syncthreads();
  int k0 = (tid>>4)*4, e0 = (tid&15)*4;
  float acc[4][4];
  #pragma unroll
  for (int i=0;i<4;i++)
    #pragma unroll
    for (int j=0;j<4;j++) acc[i][j]=0.f;
  int jmax = k0+2; if (jmax > 62) jmax = 62;
  for (int j=0; j<=jmax; ++j){
    float wv[4], tv[4];
    *(float4*)wv = *(float4*)&sW[j][k0];
    *(float4*)tv = *(float4*)&sT[j*64 + e0];
    #pragma unroll
    for (int i=0;i<4;i++)
      #pragma unroll
      for (int e=0;e<4;e++) acc[i][e] = fmaf(wv[i], tv[e], acc[i][e]);
  }
  #pragma unroll
  for (int i=0;i<4;i++){
    float4 o; o.x=acc[i][0]; o.y=acc[i][1]; o.z=acc[i][2]; o.w=acc[i][3];
    *(float4*)(Sp + (size_t)(bh*64+k0+i)*3072 + es*64 + e0) = o;
  }
}

// ----- phase3 (MFMA): GM = mask(C·B^T)*decay; O = X^T·GM^T + e^la·(Sp^T·C^T) + Dx -----
// Sp already [p][n]: staged directly (coalesced float4 + convert).
__global__ __launch_bounds__(256, 2) void k_phase3(
    const float* __restrict__ dtbuf, const float* __restrict__ lac,
    const float* __restrict__ Bm, const float* __restrict__ Cm,
    const float* __restrict__ xs, const float* __restrict__ Sp,
    const float* __restrict__ Dparam, float* __restrict__ y){
  __shared__ __align__(16) ushort_t sCh[64*72], sCl[64*72];   // C[i][n]
  __shared__ __align__(16) ushort_t sBh[64*72], sBl[64*72];   // B[s][n] -> GM[i][s]
  __shared__ __align__(16) ushort_t sXh[48*72], sXl[48*72];   // X^T[p][s]
  __shared__ __align__(16) ushort_t sPh[48*72], sPl[48*72];   // Sp^T[p][n]
  __shared__ float sla[64], sdt[64];
  int tid = threadIdx.x, blk = blockIdx.x;
  int bh = blk>>6, k = blk&63, b = bh>>3, hh = bh&7, t0 = k*64;
  int w = tid>>6, lane = tid&63, l15 = lane&15, quad = lane>>4;

  if (tid < 64){
    sdt[tid] = dtbuf[(size_t)bh*4096 + t0 + tid];
    sla[tid] = lac[(size_t)blk*64 + tid];
  }
  // ---- stage C, B (row-major, bf16 hi/lo) ----
  {
    int row = tid>>2, ng = (tid&3)*16;
    const float* csrc = Cm + (size_t)(b*4096+t0+row)*64 + ng;
    const float* bsrc = Bm + (size_t)(b*4096+t0+row)*64 + ng;
    #pragma unroll
    for (int q=0;q<4;q++){
      float4 cv = *(const float4*)(csrc + q*4);
      float4 bv = *(const float4*)(bsrc + q*4);
      ushort4 chv, clv, bhv, blv;
      chv.x=f2bf(cv.x); chv.y=f2bf(cv.y); chv.z=f2bf(cv.z); chv.w=f2bf(cv.w);
      clv.x=f2bf(cv.x-bf2f(chv.x)); clv.y=f2bf(cv.y-bf2f(chv.y));
      clv.z=f2bf(cv.z-bf2f(chv.z)); clv.w=f2bf(cv.w-bf2f(chv.w));
      bhv.x=f2bf(bv.x); bhv.y=f2bf(bv.y); bhv.z=f2bf(bv.z); bhv.w=f2bf(bv.w);
      blv.x=f2bf(bv.x-bf2f(bhv.x)); blv.y=f2bf(bv.y-bf2f(bhv.y));
      blv.z=f2bf(bv.z-bf2f(bhv.z)); blv.w=f2bf(bv.w-bf2f(bhv.w));
      int o = row*72 + ng + q*4;
      *(ushort4*)&sCh[o] = chv; *(ushort4*)&sCl[o] = clv;
      *(ushort4*)&sBh[o] = bhv; *(ushort4*)&sBl[o] = blv;
    }
  }
  // ---- stage X^T (pack-pair transpose) ----
  {
    int s2 = (tid>>3)*2, p0 = (tid&7)*6;
    const float* x0 = xs + (size_t)(bh*4096+t0+s2)*48 + p0;
    const float* x1 = x0 + 48;
    #pragma unroll
    for (int c=0;c<6;c++){
      float a0 = x0[c], a1 = x1[c];
      ushort_t h0 = f2bf(a0), h1 = f2bf(a1);
      ushort_t l0 = f2bf(a0-bf2f(h0)), l1 = f2bf(a1-bf2f(h1));
      int o = (p0+c)*72 + s2;
      *(unsigned int*)&sXh[o] = (unsigned int)h0 | ((unsigned int)h1<<16);
      *(unsigned int*)&sXl[o] = (unsigned int)l0 | ((unsigned int)l1<<16);
    }
  }
  // ---- stage Sp^T directly (already [p][n]) ----
  {
    const float* sp0 = Sp + (size_t)blk*3072;
    #pragma unroll
    for (int r=0;r<3;r++){
      int idx = tid + r*256;
      int p = idx>>4, c4 = (idx&15)*4;
      float4 v = *(const float4*)(sp0 + p*64 + c4);
      ushort4 h, l;
      h.x=f2bf(v.x); h.y=f2bf(v.y); h.z=f2bf(v.z); h.w=f2bf(v.w);
      l.x=f2bf(v.x-bf2f(h.x)); l.y=f2bf(v.y-bf2f(h.y));
      l.z=f2bf(v.z-bf2f(h.z)); l.w=f2bf(v.w-bf2f(h.w));
      *(ushort4*)&sPh[p*72 + c4] = h;
      *(ushort4*)&sPl[p*72 + c4] = l;
    }
  }
  __syncthreads();

  // ---- GM mfma: wave w owns i-band w, s-tiles 0..w ----
  f32x4 gacc[4];
  #pragma unroll
  for (int t=0;t<4;t++) gacc[t] = (f32x4)(0.f);
  {
    bf16x8 cah[2], cal[2];
    #pragma unroll
    for (int ks=0;ks<2;ks++){
      int ao = (w*16+l15)*72 + ks*32 + quad*8;
      cah[ks] = *(bf16x8*)&sCh[ao];
      cal[ks] = *(bf16x8*)&sCl[ao];
    }
    for (int bs=0; bs<=w; ++bs){
      #pragma unroll
      for (int ks=0;ks<2;ks++){
        int bo = (bs*16+l15)*72 + ks*32 + quad*8;
        bf16x8 bhf = *(bf16x8*)&sBh[bo];
        bf16x8 blf = *(bf16x8*)&sBl[bo];
        gacc[bs] = __builtin_amdgcn_mfma_f32_16x16x32_bf16(cah[ks], bhf, gacc[bs], 0,0,0);
        gacc[bs] = __builtin_amdgcn_mfma_f32_16x16x32_bf16(cah[ks], blf, gacc[bs], 0,0,0);
        gacc[bs] = __builtin_amdgcn_mfma_f32_16x16x32_bf16(cal[ks], bhf, gacc[bs], 0,0,0);
      }
    }
  }
  __syncthreads();   // sB reads done -> safe to overwrite with GM

  // ---- scale/mask, write GM bf16 hi/lo into sBh/sBl; zero needed tiles ----
  for (int bs=0; bs<=w; ++bs){
    #pragma unroll
    for (int r=0;r<4;r++){
      int i = w*16 + quad*4 + r;
      int s = bs*16 + l15;
      float v = 0.f;
      if (s <= i) v = gacc[bs][r] * __expf(sla[i]-sla[s]) * sdt[s];
      ushort_t hi = f2bf(v);
      sBh[i*72+s] = hi;
      sBl[i*72+s] = f2bf(v - bf2f(hi));
    }
  }
  if (w==0){
    #pragma unroll
    for (int r=0;r<4;r++){ sBh[(quad*4+r)*72 + 16+l15] = 0; sBl[(quad*4+r)*72 + 16+l15] = 0; }
  }
  if (w==2){
    #pragma unroll
    for (int r=0;r<4;r++){ sBh[(32+quad*4+r)*72 + 48+l15] = 0; sBl[(32+quad*4+r)*72 + 48+l15] = 0; }
  }
  __syncthreads();

  // ---- O = X^T·GM^T (intra) + Sp^T·C^T (carry); wave w owns i-tile w ----
  f32x4 accI[3], accA[3];
  #pragma unroll
  for (int t=0;t<3;t++){ accI[t] = (f32x4)(0.f); accA[t] = (f32x4)(0.f); }
  int nks = (w>=2) ? 2 : 1;
  for (int ks=0; ks<nks; ++ks){
    int go = (w*16+l15)*72 + ks*32 + quad*8;
    bf16x8 gbh = *(bf16x8*)&sBh[go];
    bf16x8 gbl = *(bf16x8*)&sBl[go];
    #pragma unroll
    for (int pt=0;pt<3;pt++){
      int xo = (pt*16+l15)*72 + ks*32 + quad*8;
      bf16x8 xah = *(bf16x8*)&sXh[xo];
      bf16x8 xal = *(bf16x8*)&sXl[xo];
      accI[pt] = __builtin_amdgcn_mfma_f32_16x16x32_bf16(xah, gbh, accI[pt], 0,0,0);
      accI[pt] = __builtin_amdgcn_mfma_f32_16x16x32_bf16(xah, gbl, accI[pt], 0,0,0);
      accI[pt] = __builtin_amdgcn_mfma_f32_16x16x32_bf16(xal, gbh, accI[pt], 0,0,0);
    }
  }
  #pragma unroll
  for (int ks=0; ks<2; ++ks){
    int co = (w*16+l15)*72 + ks*32 + quad*8;
    bf16x8 cbh = *(bf16x8*)&sCh[co];
    bf16x8 cbl = *(bf16x8*)&sCl[co];
    #pragma unroll
    for (int pt=0;pt<3;pt++){
      int po = (pt*16+l15)*72 + ks*32 + quad*8;
      bf16x8 pah = *(bf16x8*)&sPh[po];
      bf16x8 pal = *(bf16x8*)&sPl[po];
      accA[pt] = __builtin_amdgcn_mfma_f32_16x16x32_bf16(pah, cbh, accA[pt], 0,0,0);
      accA[pt] = __builtin_amdgcn_mfma_f32_16x16x32_bf16(pah, cbl, accA[pt], 0,0,0);
      accA[pt] = __builtin_amdgcn_mfma_f32_16x16x32_bf16(pal, cbh, accA[pt], 0,0,0);
    }
  }
  // ---- epilogue: Y[i][p] = accI + exp(la_i)*accA + D*x ----
  {
    int i = w*16 + l15;
    float eli = __expf(sla[i]);
    float Dh = Dparam[hh];
    float* ybase = y + (size_t)(b*4096+t0+i)*384 + hh*48;
    #pragma unroll
    for (int pt=0;pt<3;pt++)
      #pragma unroll
      for (int r=0;r<4;r++){
        int p = pt*16 + quad*4 + r;
        float xf = bf2f(sXh[p*72 + i]) + bf2f(sXl[p*72 + i]);
        ybase[p] = accI[pt][r] + eli*accA[pt][r] + Dh*xf;
      }
  }
}

// ----- gate: z recomputed from x (K=4); g=y*silu(z); RMSNorm; write yn -----
__global__ __launch_bounds__(384) void k_gate(
    const float* __restrict__ x, const float* __restrict__ Weff,
    const float* __restrict__ beff, const float* __restrict__ norm_w,
    const float* __restrict__ y, float* __restrict__ yn){
  __shared__ float sred[6];
  __shared__ float srms;
  __shared__ float sx[4];
  int bl = blockIdx.x, tid = threadIdx.x;
  if (tid < 4) sx[tid] = x[(size_t)bl*4 + tid];
  __syncthreads();
  float zv = beff[tid];
  zv = fmaf(sx[0], Weff[tid], zv);
  zv = fmaf(sx[1], Weff[904+tid], zv);
  zv = fmaf(sx[2], Weff[1808+tid], zv);
  zv = fmaf(sx[3], Weff[2712+tid], zv);
  float yv = y[(size_t)bl*384 + tid];
  float g = yv * (zv * sigmoidf_(zv));
  float ss = g*g;
  #pragma unroll
  for (int off=32; off>0; off>>=1) ss += __shfl_xor(ss, off);
  if ((tid&63)==0) sred[tid>>6] = ss;
  __syncthreads();
  if (tid==0){
    float t=0.f;
    #pragma unroll
    for (int i=0;i<6;i++) t += sred[i];
    srms = rsqrtf(t*(1.f/384.f) + 1e-5f);
  }
  __syncthreads();
  yn[(size_t)bl*384 + tid] = g * srms * norm_w[tid];
}

// ----- mlp2: 64 tokens/block, 2 tokens/thread -----
__global__ __launch_bounds__(256) void k_mlp2(
    const float* __restrict__ yn, const float* __restrict__ Weff2,
    const float* __restrict__ b1, const float* __restrict__ W2,
    const float* __restrict__ b2, float* __restrict__ macc){
  __shared__ __align__(16) float sW[384][32];
  __shared__ __align__(16) float sm1[64][33];
  __shared__ __align__(16) float sW2[32][32];
  __shared__ __align__(16) float sm2[64][33];
  int tid = threadIdx.x;
  int tok0 = blockIdx.x*64;
  int b = tok0 >> 12;
  #pragma unroll
  for (int r=0;r<12;r++){
    int idx = tid + r*256;
    int row = idx>>3, c4 = (idx&7)*4;
    *(float4*)&sW[row][c4] = *(const float4*)(Weff2 + (size_t)idx*4);
  }
  {
    int row = tid>>3, c4 = (tid&7)*4;
    *(float4*)&sW2[row][c4] = *(const float4*)(W2 + row*32 + c4);
  }
  __syncthreads();
  {
    int tk = tid>>3, j0 = (tid&7)*4;
    float a0[4], a1[4];
    #pragma unroll
    for (int j=0;j<4;j++){ a0[j] = b1[j0+j]; a1[j] = a0[j]; }
    const float* y0 = yn + (size_t)(tok0+tk)*384;
    const float* y1 = yn + (size_t)(tok0+tk+32)*384;
    for (int k4=0;k4<96;k4++){
      float4 va = *(const float4*)(y0 + k4*4);
      float4 vb = *(const float4*)(y1 + k4*4);
      float w[4];
      *(float4*)w = *(float4*)&sW[k4*4+0][j0];
      #pragma unroll
      for (int j=0;j<4;j++){ a0[j] = fmaf(va.x, w[j], a0[j]); a1[j] = fmaf(vb.x, w[j], a1[j]); }
      *(float4*)w = *(float4*)&sW[k4*4+1][j0];
      #pragma unroll
      for (int j=0;j<4;j++){ a0[j] = fmaf(va.y, w[j], a0[j]); a1[j] = fmaf(vb.y, w[j], a1[j]); }
      *(float4*)w = *(float4*)&sW[k4*4+2][j0];
      #pragma unroll
      for (int j=0;j<4;j++){ a0[j] = fmaf(va.z, w[j], a0[j]); a1[j] = fmaf(vb.z, w[j], a1[j]); }
      *(float4*)w = *(float4*)&sW[k4*4+3][j0];
      #pragma unroll
      for (int j=0;j<4;j++){ a0[j] = fmaf(va.w, w[j], a0[j]); a1[j] = fmaf(vb.w, w[j], a1[j]); }
    }
    #pragma unroll
    for (int j=0;j<4;j++){
      sm1[tk][j0+j]    = fmaxf(a0[j], 0.f);
      sm1[tk+32][j0+j] = fmaxf(a1[j], 0.f);
    }
  }
  __syncthreads();
  {
    int tk = tid>>3, j0 = (tid&7)*4;
    float a0[4], a1[4];
    #pragma unroll
    for (int j=0;j<4;j++){ a0[j] = b2[j0+j]; a1[j] = a0[j]; }
    #pragma unroll
    for (int kk=0;kk<32;kk++){
      float va = sm1[tk][kk];
      float vb = sm1[tk+32][kk];
      float w[4]; *(float4*)w = *(float4*)&sW2[kk][j0];
      #pragma unroll
      for (int j=0;j<4;j++){ a0[j] = fmaf(va, w[j], a0[j]); a1[j] = fmaf(vb, w[j], a1[j]); }
    }
    #pragma unroll
    for (int j=0;j<4;j++){
      sm2[tk][j0+j]    = fmaxf(a0[j], 0.f);
      sm2[tk+32][j0+j] = fmaxf(a1[j], 0.f);
    }
  }
  __syncthreads();
  if (tid < 32){
    float t = 0.f;
    #pragma unroll
    for (int tok=0;tok<64;tok++) t += sm2[tok][tid];
    atomicAdd(&macc[b*32 + tid], t);
  }
}

// ----- final: angle[b] = mean_m @ Wo + bo -----
__global__ void k_final(const float* __restrict__ macc, const float* __restrict__ Wo,
                        const float* __restrict__ bo, float* __restrict__ out){
  int tid = threadIdx.x;
  if (tid < 4){
    float acc = bo[0];
    #pragma unroll
    for (int j=0;j<32;j++) acc = fmaf(macc[tid*32+j]*(1.f/4096.f), Wo[j], acc);
    out[tid] = acc;
  }
}

// ---------------------------------------------------------------------------
extern "C" void kernel_launch(void* const* d_in, const int* in_sizes, int n_in,
                              void* d_out, int out_size, void* d_ws, size_t ws_size,
                              hipStream_t stream){
  const float* x      = (const float*)d_in[0];
  const float* Wfc    = (const float*)d_in[1];
  const float* bfc    = (const float*)d_in[2];
  const float* W_in   = (const float*)d_in[3];
  const float* conv_w = (const float*)d_in[4];
  const float* conv_b = (const float*)d_in[5];
  const float* dt_bias= (const float*)d_in[6];
  const float* A_log  = (const float*)d_in[7];
  const float* Dparam = (const float*)d_in[8];
  const float* norm_w = (const float*)d_in[9];
  const float* W_out  = (const float*)d_in[10];
  const float* W1     = (const float*)d_in[11];
  const float* b1     = (const float*)d_in[12];
  const float* W2     = (const float*)d_in[13];
  const float* b2     = (const float*)d_in[14];
  const float* Wo     = (const float*)d_in[15];
  const float* bo     = (const float*)d_in[16];
  float* ws  = (float*)d_ws;
  float* out = (float*)d_out;

  float* Weff  = ws + OFF_W;
  float* beff  = ws + OFF_W + 4096;
  float* Weff2 = ws + OFF_W + 8192;
  float* yn    = ws + OFF_Z;
  float* Tb    = ws + OFF_T;
  float* xsb   = ws + OFF_XS;
  float* Bmb   = ws + OFF_BM;
  float* Cmb   = ws + OFF_CM;
  float* dtb   = ws + OFF_DT;
  float* lacb  = ws + OFF_LAC;
  float* Spb   = ws + OFF_SP;
  float* yb    = ws + OFF_Y;
  float* macc  = ws + OFF_MACC;

  k_prep<<<dim3(52), dim3(256), 0, stream>>>(Wfc, bfc, W_in, W_out, W1,
                                             Weff, beff, Weff2, macc);
  k_ipc<<<dim3(BL), dim3(256), 0, stream>>>(x, Weff, beff, conv_w, conv_b,
                                            dt_bias, xsb, Bmb, Cmb, dtb);
  k_phase1<<<dim3(BH*NC), dim3(256), 0, stream>>>(dtb, Bmb, xsb, A_log, Tb, lacb);
  k_phase2p<<<dim3(BH,48), dim3(256), 0, stream>>>(Tb, lacb, Spb);
  k_phase3<<<dim3(BH*NC), dim3(256), 0, stream>>>(dtb, lacb, Bmb, Cmb, xsb, Spb, Dparam, yb);
  k_gate<<<dim3(BL), dim3(384), 0, stream>>>(x, Weff, beff, norm_w, yb, yn);
  k_mlp2<<<dim3(BL/64), dim3(256), 0, stream>>>(yn, Weff2, b1, W2, b2, macc);
  k_final<<<dim3(1), dim3(64), 0, stream>>>(macc, Wo, bo, out);
}